// Round 2
// baseline (3692.510 us; speedup 1.0000x reference)
//
#include <hip/hip_runtime.h>
#include <math.h>

#define H 1024
#define V 32000
#define B 64
#define S 64
#define T 13

typedef __attribute__((ext_vector_type(8))) short bf16x8;
typedef __attribute__((ext_vector_type(4))) float f32x4;

__device__ __forceinline__ float sigmoidf_fast(float x) { return 1.0f / (1.0f + __expf(-x)); }

__device__ __forceinline__ unsigned short f2bf(float x) {
    union { float f; unsigned u; } v; v.f = x;
    unsigned r = v.u + 0x7fffu + ((v.u >> 16) & 1u);
    return (unsigned short)(r >> 16);
}

// C[by*64+b, n] = bias[n] + sum_k A[by*64+b, k] * W[n, k]
// grid (N/64, M/64, KS). KS>1 -> atomicAdd partials (C pre-initialized with bias).
__global__ void gemm_tn(const float* __restrict__ A, const float* __restrict__ W,
                        const float* __restrict__ bias, float* __restrict__ C,
                        int N, int K, int ldC) {
    __shared__ float As[16][64];
    __shared__ float Ws[16][64];
    const int tid = threadIdx.x;
    const int tx = tid & 15, ty = tid >> 4;
    const int bx = blockIdx.x, by = blockIdx.y;
    const int Kc = K / gridDim.z;
    const int k_begin = blockIdx.z * Kc, k_end = k_begin + Kc;
    const float* Ab = A + (size_t)by * 64 * K;
    const float* Wb = W + (size_t)bx * 64 * K;
    const int lb = tid >> 2, lk = (tid & 3) * 4;
    float acc[4][4] = {};
    for (int k0 = k_begin; k0 < k_end; k0 += 16) {
        float4 av = *(const float4*)(Ab + (size_t)lb * K + k0 + lk);
        float4 wv = *(const float4*)(Wb + (size_t)lb * K + k0 + lk);
        As[lk + 0][lb] = av.x; As[lk + 1][lb] = av.y; As[lk + 2][lb] = av.z; As[lk + 3][lb] = av.w;
        Ws[lk + 0][lb] = wv.x; Ws[lk + 1][lb] = wv.y; Ws[lk + 2][lb] = wv.z; Ws[lk + 3][lb] = wv.w;
        __syncthreads();
#pragma unroll
        for (int k = 0; k < 16; ++k) {
            float4 a = *(const float4*)(&As[k][ty * 4]);
            float4 w = *(const float4*)(&Ws[k][tx * 4]);
            acc[0][0] += a.x * w.x; acc[0][1] += a.x * w.y; acc[0][2] += a.x * w.z; acc[0][3] += a.x * w.w;
            acc[1][0] += a.y * w.x; acc[1][1] += a.y * w.y; acc[1][2] += a.y * w.z; acc[1][3] += a.y * w.w;
            acc[2][0] += a.z * w.x; acc[2][1] += a.z * w.y; acc[2][2] += a.z * w.z; acc[2][3] += a.z * w.w;
            acc[3][0] += a.w * w.x; acc[3][1] += a.w * w.y; acc[3][2] += a.w * w.z; acc[3][3] += a.w * w.w;
        }
        __syncthreads();
    }
    const int n0 = bx * 64 + tx * 4;
    if (gridDim.z > 1) {
#pragma unroll
        for (int i = 0; i < 4; ++i) {
            float* Cp = C + (size_t)(by * 64 + ty * 4 + i) * ldC + n0;
            atomicAdd(&Cp[0], acc[i][0]); atomicAdd(&Cp[1], acc[i][1]);
            atomicAdd(&Cp[2], acc[i][2]); atomicAdd(&Cp[3], acc[i][3]);
        }
    } else {
        float4 bv = bias ? *(const float4*)(bias + n0) : make_float4(0.f, 0.f, 0.f, 0.f);
#pragma unroll
        for (int i = 0; i < 4; ++i) {
            float* Cp = C + (size_t)(by * 64 + ty * 4 + i) * ldC + n0;
            float4 o;
            o.x = acc[i][0] + bv.x; o.y = acc[i][1] + bv.y;
            o.z = acc[i][2] + bv.z; o.w = acc[i][3] + bv.w;
            *(float4*)Cp = o;
        }
    }
}

// Per step: gather embedding into xi[:, :H], init q with ba, init gates with b_ih+b_hh.
__global__ void embed_init(const int* __restrict__ target, const float* __restrict__ emb,
                           const float* __restrict__ ba, const float* __restrict__ b_ih,
                           const float* __restrict__ b_hh,
                           float* __restrict__ xi, float* __restrict__ q,
                           float* __restrict__ gates, int t) {
    const int b = blockIdx.x, tid = threadIdx.x;
    const int tok = (t == 0) ? 2 : target[b * T + t - 1];
    ((float4*)(xi + (size_t)b * 2 * H))[tid] = ((const float4*)(emb + (size_t)tok * H))[tid];
    ((float4*)(q + (size_t)b * H))[tid] = ((const float4*)ba)[tid];
    const float4* bi4 = (const float4*)b_ih;
    const float4* bh4 = (const float4*)b_hh;
    float4* g4 = (float4*)(gates + (size_t)b * 4 * H);
#pragma unroll
    for (int j = 0; j < 4; ++j) {
        int idx = tid + j * 256;
        float4 a = bi4[idx], bb = bh4[idx];
        g4[idx] = make_float4(a.x + bb.x, a.y + bb.y, a.z + bb.z, a.w + bb.w);
    }
}

// One block per batch row: scores = Va . tanh(q + keys_proj), softmax over S, ctx = w @ enc_out.
__global__ void attn_ctx(const float* __restrict__ q, const float* __restrict__ keys_proj,
                         const float* __restrict__ enc_out, const float* __restrict__ Va,
                         float* __restrict__ xi, float* __restrict__ attn_out, int t) {
    const int b = blockIdx.x, tid = threadIdx.x;
    __shared__ float qs[H];
    __shared__ float vas[H];
    __shared__ float sw[S];
    const float* qb = q + (size_t)b * H;
    for (int i = tid; i < H; i += 256) { qs[i] = qb[i]; vas[i] = Va[i]; }
    __syncthreads();
    const int s = tid >> 2, hq = tid & 3;
    const float* kp = keys_proj + ((size_t)b * S + s) * H;
    float part = 0.f;
    for (int j = 0; j < H / 4; ++j) {
        int hh = j * 4 + hq;
        part += vas[hh] * tanhf(qs[hh] + kp[hh]);
    }
    part += __shfl_xor(part, 1);
    part += __shfl_xor(part, 2);
    if (hq == 0) sw[s] = part;
    __syncthreads();
    if (tid < 64) {
        float v = sw[tid];
        float m = v;
#pragma unroll
        for (int o = 32; o; o >>= 1) m = fmaxf(m, __shfl_xor(m, o));
        float e = __expf(v - m);
        float ssum = e;
#pragma unroll
        for (int o = 32; o; o >>= 1) ssum += __shfl_xor(ssum, o);
        float w = e / ssum;
        sw[tid] = w;
        attn_out[((size_t)b * T + t) * S + tid] = w;
    }
    __syncthreads();
    const float* Eb = enc_out + (size_t)b * S * H;
    float a0 = 0.f, a1 = 0.f, a2 = 0.f, a3 = 0.f;
    for (int s2 = 0; s2 < S; ++s2) {
        float w = sw[s2];
        const float* row = Eb + (size_t)s2 * H;
        a0 += w * row[tid];
        a1 += w * row[tid + 256];
        a2 += w * row[tid + 512];
        a3 += w * row[tid + 768];
    }
    float* ctx = xi + (size_t)b * 2 * H + H;
    ctx[tid] = a0; ctx[tid + 256] = a1; ctx[tid + 512] = a2; ctx[tid + 768] = a3;
}

// One block per batch row: LSTM cell (torch i,f,g,o order) + LayerNorm into nh (bf16).
__global__ void cell_ln(const float* __restrict__ gates, float* __restrict__ h,
                        float* __restrict__ c, unsigned short* __restrict__ nhb,
                        const float* __restrict__ ln_g, const float* __restrict__ ln_b) {
    const int b = blockIdx.x, tid = threadIdx.x;
    const float* gb = gates + (size_t)b * 4 * H;
    float* cb = c + (size_t)b * H;
    float* hb = h + (size_t)b * H;
    float hv[4];
    float sum = 0.f, sumsq = 0.f;
#pragma unroll
    for (int j = 0; j < 4; ++j) {
        int n = tid + j * 256;
        float ig = sigmoidf_fast(gb[n]);
        float fg = sigmoidf_fast(gb[n + H]);
        float gg = tanhf(gb[n + 2 * H]);
        float og = sigmoidf_fast(gb[n + 3 * H]);
        float cv = fg * cb[n] + ig * gg;
        cb[n] = cv;
        float hn = og * tanhf(cv);
        hb[n] = hn;
        hv[j] = hn;
        sum += hn;
        sumsq += hn * hn;
    }
#pragma unroll
    for (int o = 32; o; o >>= 1) { sum += __shfl_xor(sum, o); sumsq += __shfl_xor(sumsq, o); }
    __shared__ float rs[4], rq[4];
    if ((tid & 63) == 0) { rs[tid >> 6] = sum; rq[tid >> 6] = sumsq; }
    __syncthreads();
    sum = rs[0] + rs[1] + rs[2] + rs[3];
    sumsq = rq[0] + rq[1] + rq[2] + rq[3];
    float mu = sum * (1.f / H);
    float var = sumsq * (1.f / H) - mu * mu;
    float inv = rsqrtf(var + 1e-5f);
#pragma unroll
    for (int j = 0; j < 4; ++j) {
        int n = tid + j * 256;
        nhb[(size_t)b * H + n] = f2bf((hv[j] - mu) * inv * ln_g[n] + ln_b[n]);
    }
}

// One-time fp32 -> bf16 conversion of outW (V*H elements), 4 per thread.
__global__ void convert_w_bf16(const float* __restrict__ src, unsigned short* __restrict__ dst) {
    size_t i = ((size_t)blockIdx.x * 256 + threadIdx.x) * 4;
    float4 v = *(const float4*)(src + i);
    ushort4 o;
    o.x = f2bf(v.x); o.y = f2bf(v.y); o.z = f2bf(v.z); o.w = f2bf(v.w);
    *(ushort4*)(dst + i) = o;
}

// logits[64 x 32000] = nh_bf16[64 x 1024] @ outW^T + outb via bf16 MFMA.
// Register-direct version: NO LDS, NO barriers. MFMA frag layout (harness-verified
// in the previous LDS version): lane holds row (l&15), k-chunk (l>>4)*8 -> a b128
// global load IS the fragment. A (128 KB) is L1/L2-hot (all 4 waves load identical
// addresses); W streams from L3. Grid V/64 = 500 blocks = ~2 blocks/CU, 2 waves/SIMD,
// unroll-4 keeps ~20 independent b128 loads in flight per wave.
template <int SRC_BF16>
__global__ __launch_bounds__(256, 2)
void logits_mfma(const unsigned short* __restrict__ Abf, const float* __restrict__ Wf32,
                 const unsigned short* __restrict__ Wbf, const float* __restrict__ outb,
                 float* __restrict__ C) {
    const int tid = threadIdx.x;
    const int l = tid & 63, w = tid >> 6;
    const int l15 = l & 15, lq = l >> 4;
    const int n = blockIdx.x * 64 + w * 16 + l15;   // this lane's output column
    const unsigned short* Ab = Abf + (size_t)l15 * H + lq * 8;
    const unsigned short* Wb = Wbf + (size_t)n * H + lq * 8;
    const float* Wf = Wf32 + (size_t)n * H + lq * 8;
    const float bv = outb[n];
    f32x4 acc[4] = {};
#pragma unroll 4
    for (int k0 = 0; k0 < H; k0 += 32) {
        bf16x8 wf;
        if (SRC_BF16) {
            wf = *(const bf16x8*)(Wb + k0);
        } else {
            float4 w0 = *(const float4*)(Wf + k0);
            float4 w1 = *(const float4*)(Wf + k0 + 4);
            union { bf16x8 v; unsigned short u[8]; } cv;
            cv.u[0] = f2bf(w0.x); cv.u[1] = f2bf(w0.y); cv.u[2] = f2bf(w0.z); cv.u[3] = f2bf(w0.w);
            cv.u[4] = f2bf(w1.x); cv.u[5] = f2bf(w1.y); cv.u[6] = f2bf(w1.z); cv.u[7] = f2bf(w1.w);
            wf = cv.v;
        }
        bf16x8 a0 = *(const bf16x8*)(Ab + k0);
        bf16x8 a1 = *(const bf16x8*)(Ab + 16 * H + k0);
        bf16x8 a2 = *(const bf16x8*)(Ab + 32 * H + k0);
        bf16x8 a3 = *(const bf16x8*)(Ab + 48 * H + k0);
        acc[0] = __builtin_amdgcn_mfma_f32_16x16x32_bf16(a0, wf, acc[0], 0, 0, 0);
        acc[1] = __builtin_amdgcn_mfma_f32_16x16x32_bf16(a1, wf, acc[1], 0, 0, 0);
        acc[2] = __builtin_amdgcn_mfma_f32_16x16x32_bf16(a2, wf, acc[2], 0, 0, 0);
        acc[3] = __builtin_amdgcn_mfma_f32_16x16x32_bf16(a3, wf, acc[3], 0, 0, 0);
    }
    // Epilogue: C/D mapping col = lane&15, row = (lane>>4)*4 + reg (m89-verified).
#pragma unroll
    for (int mf = 0; mf < 4; ++mf) {
        const int m = mf * 16 + lq * 4;
#pragma unroll
        for (int r = 0; r < 4; ++r)
            C[(size_t)(m + r) * ((size_t)T * V) + n] = acc[mf][r] + bv;
    }
}

// In-place log-softmax over V for row (b, t) of logp.
__global__ void logsoftmax_inplace(float* __restrict__ out, int t) {
    const int b = blockIdx.x, tid = threadIdx.x;
    float* row = out + ((size_t)b * T + t) * V;
    float m = -3.4e38f;
    for (int v = tid; v < V; v += 256) m = fmaxf(m, row[v]);
#pragma unroll
    for (int o = 32; o; o >>= 1) m = fmaxf(m, __shfl_xor(m, o));
    __shared__ float red[4];
    if ((tid & 63) == 0) red[tid >> 6] = m;
    __syncthreads();
    m = fmaxf(fmaxf(red[0], red[1]), fmaxf(red[2], red[3]));
    float ssum = 0.f;
    for (int v = tid; v < V; v += 256) ssum += __expf(row[v] - m);
#pragma unroll
    for (int o = 32; o; o >>= 1) ssum += __shfl_xor(ssum, o);
    __shared__ float red2[4];
    if ((tid & 63) == 0) red2[tid >> 6] = ssum;
    __syncthreads();
    ssum = red2[0] + red2[1] + red2[2] + red2[3];
    float L = m + logf(ssum);
    for (int v = tid; v < V; v += 256) row[v] -= L;
}

// Copy two 64x1024 f32 buffers (used for h/c init and final h/c output).
__global__ void copy2(const float* __restrict__ a, const float* __restrict__ bsrc,
                      float* __restrict__ x, float* __restrict__ y) {
    size_t i = (size_t)blockIdx.x * 256 + threadIdx.x;
    ((float4*)x)[i] = ((const float4*)a)[i];
    ((float4*)y)[i] = ((const float4*)bsrc)[i];
}

extern "C" void kernel_launch(void* const* d_in, const int* in_sizes, int n_in,
                              void* d_out, int out_size, void* d_ws, size_t ws_size,
                              hipStream_t stream) {
    const float* enc_out = (const float*)d_in[0];
    const float* enc_h   = (const float*)d_in[1];
    const float* enc_c   = (const float*)d_in[2];
    const int*   target  = (const int*)d_in[3];
    const float* emb     = (const float*)d_in[4];
    const float* Wa      = (const float*)d_in[5];
    const float* ba      = (const float*)d_in[6];
    const float* Ua      = (const float*)d_in[7];
    const float* bu      = (const float*)d_in[8];
    const float* Va      = (const float*)d_in[9];
    // d_in[10] = bv: adds a constant to all scores -> cancels in softmax; omitted.
    const float* W_ih    = (const float*)d_in[11];
    const float* W_hh    = (const float*)d_in[12];
    const float* b_ih    = (const float*)d_in[13];
    const float* b_hh    = (const float*)d_in[14];
    const float* ln_g    = (const float*)d_in[15];
    const float* ln_b    = (const float*)d_in[16];
    const float* outW    = (const float*)d_in[17];
    const float* outb    = (const float*)d_in[18];
    float* out = (float*)d_out;

    float* ws    = (float*)d_ws;
    float* keys  = ws;                          // B*S*H
    float* h     = keys + (size_t)B * S * H;    // B*H
    float* c     = h + (size_t)B * H;           // B*H
    float* q     = c + (size_t)B * H;           // B*H
    float* xi    = q + (size_t)B * H;           // B*2H  (x | ctx)
    float* gates = xi + (size_t)B * 2 * H;      // B*4H
    float* nhs   = gates + (size_t)B * 4 * H;   // B*H slot, used as bf16
    unsigned short* nhb = (unsigned short*)nhs;

    const size_t base_floats = (size_t)B * S * H + 3 * (size_t)B * H
                             + (size_t)B * 2 * H + (size_t)B * 4 * H + (size_t)B * H;
    unsigned short* outWb = (unsigned short*)(ws + base_floats);
    const size_t need = base_floats * sizeof(float) + (size_t)V * H * sizeof(unsigned short);
    const int pre = (ws_size >= need);

    const size_t HOFF = (size_t)B * T * V;
    const size_t COFF = HOFF + (size_t)B * H;
    const size_t AOFF = COFF + (size_t)B * H;

    // One-time: outW fp32 -> bf16 (only if the workspace has room; else the
    // MFMA kernel converts in its staging loads).
    if (pre)
        hipLaunchKernelGGL(convert_w_bf16, dim3((V * H) / 1024), dim3(256), 0, stream, outW, outWb);

    // keys_proj = enc_out @ Ua^T + bu   [B*S, H]
    hipLaunchKernelGGL(gemm_tn, dim3(H / 64, (B * S) / 64, 1), dim3(256), 0, stream,
                       enc_out, Ua, bu, keys, H, H, H);
    hipLaunchKernelGGL(copy2, dim3(64), dim3(256), 0, stream, enc_h, enc_c, h, c);

    for (int t = 0; t < T; ++t) {
        hipLaunchKernelGGL(embed_init, dim3(B), dim3(256), 0, stream,
                           target, emb, ba, b_ih, b_hh, xi, q, gates, t);
        // q = h @ Wa^T + ba   (split-K=4 atomic; bias pre-init in embed_init)
        hipLaunchKernelGGL(gemm_tn, dim3(H / 64, 1, 4), dim3(256), 0, stream,
                           h, Wa, nullptr, q, H, H, H);
        hipLaunchKernelGGL(attn_ctx, dim3(B), dim3(256), 0, stream,
                           q, keys, enc_out, Va, xi, out + AOFF, t);
        // gates = xi @ W_ih^T + h @ W_hh^T + b_ih + b_hh  (split-K atomic)
        hipLaunchKernelGGL(gemm_tn, dim3(4 * H / 64, 1, 4), dim3(256), 0, stream,
                           xi, W_ih, nullptr, gates, 4 * H, 2 * H, 4 * H);
        hipLaunchKernelGGL(gemm_tn, dim3(4 * H / 64, 1, 4), dim3(256), 0, stream,
                           h, W_hh, nullptr, gates, 4 * H, H, 4 * H);
        hipLaunchKernelGGL(cell_ln, dim3(B), dim3(256), 0, stream,
                           gates, h, c, nhb, ln_g, ln_b);
        // logits straight into logp slot (row stride T*V) via bf16 MFMA
        if (pre)
            hipLaunchKernelGGL((logits_mfma<1>), dim3(V / 64), dim3(256), 0, stream,
                               nhb, nullptr, outWb, outb, out + (size_t)t * V);
        else
            hipLaunchKernelGGL((logits_mfma<0>), dim3(V / 64), dim3(256), 0, stream,
                               nhb, outW, nullptr, outb, out + (size_t)t * V);
        hipLaunchKernelGGL(logsoftmax_inplace, dim3(B), dim3(256), 0, stream, out, t);
    }
    hipLaunchKernelGGL(copy2, dim3(64), dim3(256), 0, stream, h, c, out + HOFF, out + COFF);
}

// Round 4
// 2846.504 us; speedup vs baseline: 1.2972x; 1.2972x over previous
//
#include <hip/hip_runtime.h>
#include <math.h>

#define H 1024
#define V 32000
#define B 64
#define S 64
#define T 13
#define MROWS (B * T)   // 832 batched logits rows

typedef __attribute__((ext_vector_type(8))) short bf16x8;
typedef __attribute__((ext_vector_type(4))) float f32x4;

__device__ __forceinline__ float sigmoidf_fast(float x) { return 1.0f / (1.0f + __expf(-x)); }

__device__ __forceinline__ unsigned short f2bf(float x) {
    union { float f; unsigned u; } v; v.f = x;
    unsigned r = v.u + 0x7fffu + ((v.u >> 16) & 1u);
    return (unsigned short)(r >> 16);
}

// 2 f32 -> packed 2x bf16 (lo = a, hi = b), RNE. No builtin on gfx950 (m240) -> asm.
__device__ __forceinline__ unsigned cvt_pk_bf16(float a, float b) {
    unsigned r;
    asm volatile("v_cvt_pk_bf16_f32 %0, %1, %2" : "=v"(r) : "v"(a), "v"(b));
    return r;
}

// C[by*64+b, n] = bias[n] + sum_k A[by*64+b, k] * W[n, k]
// grid (N/64, M/64, KS). KS>1 -> atomicAdd partials (C pre-initialized with bias).
__global__ void gemm_tn(const float* __restrict__ A, const float* __restrict__ W,
                        const float* __restrict__ bias, float* __restrict__ C,
                        int N, int K, int ldC) {
    __shared__ float As[16][64];
    __shared__ float Ws[16][64];
    const int tid = threadIdx.x;
    const int tx = tid & 15, ty = tid >> 4;
    const int bx = blockIdx.x, by = blockIdx.y;
    const int Kc = K / gridDim.z;
    const int k_begin = blockIdx.z * Kc, k_end = k_begin + Kc;
    const float* Ab = A + (size_t)by * 64 * K;
    const float* Wb = W + (size_t)bx * 64 * K;
    const int lb = tid >> 2, lk = (tid & 3) * 4;
    float acc[4][4] = {};
    for (int k0 = k_begin; k0 < k_end; k0 += 16) {
        float4 av = *(const float4*)(Ab + (size_t)lb * K + k0 + lk);
        float4 wv = *(const float4*)(Wb + (size_t)lb * K + k0 + lk);
        As[lk + 0][lb] = av.x; As[lk + 1][lb] = av.y; As[lk + 2][lb] = av.z; As[lk + 3][lb] = av.w;
        Ws[lk + 0][lb] = wv.x; Ws[lk + 1][lb] = wv.y; Ws[lk + 2][lb] = wv.z; Ws[lk + 3][lb] = wv.w;
        __syncthreads();
#pragma unroll
        for (int k = 0; k < 16; ++k) {
            float4 a = *(const float4*)(&As[k][ty * 4]);
            float4 w = *(const float4*)(&Ws[k][tx * 4]);
            acc[0][0] += a.x * w.x; acc[0][1] += a.x * w.y; acc[0][2] += a.x * w.z; acc[0][3] += a.x * w.w;
            acc[1][0] += a.y * w.x; acc[1][1] += a.y * w.y; acc[1][2] += a.y * w.z; acc[1][3] += a.y * w.w;
            acc[2][0] += a.z * w.x; acc[2][1] += a.z * w.y; acc[2][2] += a.z * w.z; acc[2][3] += a.z * w.w;
            acc[3][0] += a.w * w.x; acc[3][1] += a.w * w.y; acc[3][2] += a.w * w.z; acc[3][3] += a.w * w.w;
        }
        __syncthreads();
    }
    const int n0 = bx * 64 + tx * 4;
    if (gridDim.z > 1) {
#pragma unroll
        for (int i = 0; i < 4; ++i) {
            float* Cp = C + (size_t)(by * 64 + ty * 4 + i) * ldC + n0;
            atomicAdd(&Cp[0], acc[i][0]); atomicAdd(&Cp[1], acc[i][1]);
            atomicAdd(&Cp[2], acc[i][2]); atomicAdd(&Cp[3], acc[i][3]);
        }
    } else {
        float4 bv = bias ? *(const float4*)(bias + n0) : make_float4(0.f, 0.f, 0.f, 0.f);
#pragma unroll
        for (int i = 0; i < 4; ++i) {
            float* Cp = C + (size_t)(by * 64 + ty * 4 + i) * ldC + n0;
            float4 o;
            o.x = acc[i][0] + bv.x; o.y = acc[i][1] + bv.y;
            o.z = acc[i][2] + bv.z; o.w = acc[i][3] + bv.w;
            *(float4*)Cp = o;
        }
    }
}

// Per step: gather embedding into xi[:, :H], init q with ba, init gates with b_ih+b_hh.
__global__ void embed_init(const int* __restrict__ target, const float* __restrict__ emb,
                           const float* __restrict__ ba, const float* __restrict__ b_ih,
                           const float* __restrict__ b_hh,
                           float* __restrict__ xi, float* __restrict__ q,
                           float* __restrict__ gates, int t) {
    const int b = blockIdx.x, tid = threadIdx.x;
    const int tok = (t == 0) ? 2 : target[b * T + t - 1];
    ((float4*)(xi + (size_t)b * 2 * H))[tid] = ((const float4*)(emb + (size_t)tok * H))[tid];
    ((float4*)(q + (size_t)b * H))[tid] = ((const float4*)ba)[tid];
    const float4* bi4 = (const float4*)b_ih;
    const float4* bh4 = (const float4*)b_hh;
    float4* g4 = (float4*)(gates + (size_t)b * 4 * H);
#pragma unroll
    for (int j = 0; j < 4; ++j) {
        int idx = tid + j * 256;
        float4 a = bi4[idx], bb = bh4[idx];
        g4[idx] = make_float4(a.x + bb.x, a.y + bb.y, a.z + bb.z, a.w + bb.w);
    }
}

// One block per batch row: scores = Va . tanh(q + keys_proj), softmax over S, ctx = w @ enc_out.
__global__ void attn_ctx(const float* __restrict__ q, const float* __restrict__ keys_proj,
                         const float* __restrict__ enc_out, const float* __restrict__ Va,
                         float* __restrict__ xi, float* __restrict__ attn_out, int t) {
    const int b = blockIdx.x, tid = threadIdx.x;
    __shared__ float qs[H];
    __shared__ float vas[H];
    __shared__ float sw[S];
    const float* qb = q + (size_t)b * H;
    for (int i = tid; i < H; i += 256) { qs[i] = qb[i]; vas[i] = Va[i]; }
    __syncthreads();
    const int s = tid >> 2, hq = tid & 3;
    const float* kp = keys_proj + ((size_t)b * S + s) * H;
    float part = 0.f;
    for (int j = 0; j < H / 4; ++j) {
        int hh = j * 4 + hq;
        part += vas[hh] * tanhf(qs[hh] + kp[hh]);
    }
    part += __shfl_xor(part, 1);
    part += __shfl_xor(part, 2);
    if (hq == 0) sw[s] = part;
    __syncthreads();
    if (tid < 64) {
        float v = sw[tid];
        float m = v;
#pragma unroll
        for (int o = 32; o; o >>= 1) m = fmaxf(m, __shfl_xor(m, o));
        float e = __expf(v - m);
        float ssum = e;
#pragma unroll
        for (int o = 32; o; o >>= 1) ssum += __shfl_xor(ssum, o);
        float w = e / ssum;
        sw[tid] = w;
        attn_out[((size_t)b * T + t) * S + tid] = w;
    }
    __syncthreads();
    const float* Eb = enc_out + (size_t)b * S * H;
    float a0 = 0.f, a1 = 0.f, a2 = 0.f, a3 = 0.f;
    for (int s2 = 0; s2 < S; ++s2) {
        float w = sw[s2];
        const float* row = Eb + (size_t)s2 * H;
        a0 += w * row[tid];
        a1 += w * row[tid + 256];
        a2 += w * row[tid + 512];
        a3 += w * row[tid + 768];
    }
    float* ctx = xi + (size_t)b * 2 * H + H;
    ctx[tid] = a0; ctx[tid + 256] = a1; ctx[tid + 512] = a2; ctx[tid + 768] = a3;
}

// One block per batch row: LSTM cell + LayerNorm. nh written as bf16.
__global__ void cell_ln(const float* __restrict__ gates, float* __restrict__ h,
                        float* __restrict__ c, unsigned short* __restrict__ nhb,
                        const float* __restrict__ ln_g, const float* __restrict__ ln_b) {
    const int b = blockIdx.x, tid = threadIdx.x;
    const float* gb = gates + (size_t)b * 4 * H;
    float* cb = c + (size_t)b * H;
    float* hb = h + (size_t)b * H;
    float hv[4];
    float sum = 0.f, sumsq = 0.f;
#pragma unroll
    for (int j = 0; j < 4; ++j) {
        int n = tid + j * 256;
        float ig = sigmoidf_fast(gb[n]);
        float fg = sigmoidf_fast(gb[n + H]);
        float gg = tanhf(gb[n + 2 * H]);
        float og = sigmoidf_fast(gb[n + 3 * H]);
        float cv = fg * cb[n] + ig * gg;
        cb[n] = cv;
        float hn = og * tanhf(cv);
        hb[n] = hn;
        hv[j] = hn;
        sum += hn;
        sumsq += hn * hn;
    }
#pragma unroll
    for (int o = 32; o; o >>= 1) { sum += __shfl_xor(sum, o); sumsq += __shfl_xor(sumsq, o); }
    __shared__ float rs[4], rq[4];
    if ((tid & 63) == 0) { rs[tid >> 6] = sum; rq[tid >> 6] = sumsq; }
    __syncthreads();
    sum = rs[0] + rs[1] + rs[2] + rs[3];
    sumsq = rq[0] + rq[1] + rq[2] + rq[3];
    float mu = sum * (1.f / H);
    float var = sumsq * (1.f / H) - mu * mu;
    float inv = rsqrtf(var + 1e-5f);
#pragma unroll
    for (int j = 0; j < 4; ++j) {
        int n = tid + j * 256;
        nhb[(size_t)b * H + n] = f2bf((hv[j] - mu) * inv * ln_g[n] + ln_b[n]);
    }
}

// Batched logits: out_logits[m, n] = nhall[m, :] . outW[n, :] + outb[n]
// m = t*B + b  ->  written to out[(b*T + t)*V + n]  (the logp slab).
// M=832, N=32000, K=1024, bf16 MFMA. BM=128 (7 m-blocks, guarded), BN=64, BK=64.
// 256 thr = 4 waves (2x2), per-wave 64x32 (mf=4, nf=2, ks=2 -> 16 MFMA/iter).
// Double-buffered LDS, reg-staged (W converts f32->bf16 via v_cvt_pk), ONE barrier
// per k-iter (write goes to the other buffer; WAR separated by previous barrier).
// XOR swizzle byte ^= (row&7)<<4 on 128B rows = G4-verified conflict-free ds_read_b128.
__global__ __launch_bounds__(256, 4)
void logits_batched(const unsigned short* __restrict__ Abf, const float* __restrict__ Wf,
                    const float* __restrict__ outb, float* __restrict__ out) {
    __shared__ unsigned short Al[2][128 * 64];  // 16 KB per buffer
    __shared__ unsigned short Wl[2][64 * 64];   //  8 KB per buffer
    const int tid = threadIdx.x;
    const int n0 = blockIdx.x * 64;
    const int m0 = blockIdx.y * 128;
    const int w = tid >> 6, l = tid & 63;
    const int wm = w >> 1, wn = w & 1;          // 2x2 wave grid
    const int l15 = l & 15, lq = l >> 4;

    // A staging: 2 threads/row, 4 chunks (32 bf16 = 64B) each
    const int ar = tid >> 1, ac4 = (tid & 1) * 4;
    // W staging: 4 threads/row, 16 f32 (64B) each -> 2 bf16 chunks
    const int wr = tid >> 2, wc = tid & 3;

    uint4 areg[4];
    float4 wreg[4];
    f32x4 acc[4][2] = {};

    auto LOADT = [&](int k0) {
        const int gm = m0 + ar;
        if (gm < MROWS) {
            const unsigned short* Ap = Abf + (size_t)gm * H + k0 + ac4 * 8;
#pragma unroll
            for (int j = 0; j < 4; ++j) areg[j] = ((const uint4*)Ap)[j];
        } else {
            uint4 z = {0, 0, 0, 0};
#pragma unroll
            for (int j = 0; j < 4; ++j) areg[j] = z;
        }
        const float* Wp = Wf + (size_t)(n0 + wr) * H + k0 + wc * 16;
#pragma unroll
        for (int j = 0; j < 4; ++j) wreg[j] = ((const float4*)Wp)[j];
    };
    auto WRITET = [&](int buf) {
        char* Ab = (char*)Al[buf];
#pragma unroll
        for (int j = 0; j < 4; ++j)
            *(uint4*)(Ab + (ar * 128 + (((ac4 + j) * 16) ^ ((ar & 7) << 4)))) = areg[j];
        // 16 f32 -> 16 bf16 (8 cvt_pk) -> 2 x 16B chunks
        unsigned wp[8];
        wp[0] = cvt_pk_bf16(wreg[0].x, wreg[0].y); wp[1] = cvt_pk_bf16(wreg[0].z, wreg[0].w);
        wp[2] = cvt_pk_bf16(wreg[1].x, wreg[1].y); wp[3] = cvt_pk_bf16(wreg[1].z, wreg[1].w);
        wp[4] = cvt_pk_bf16(wreg[2].x, wreg[2].y); wp[5] = cvt_pk_bf16(wreg[2].z, wreg[2].w);
        wp[6] = cvt_pk_bf16(wreg[3].x, wreg[3].y); wp[7] = cvt_pk_bf16(wreg[3].z, wreg[3].w);
        char* Wb = (char*)Wl[buf];
        *(uint4*)(Wb + (wr * 128 + (((2 * wc) * 16) ^ ((wr & 7) << 4)))) =
            make_uint4(wp[0], wp[1], wp[2], wp[3]);
        *(uint4*)(Wb + (wr * 128 + (((2 * wc + 1) * 16) ^ ((wr & 7) << 4)))) =
            make_uint4(wp[4], wp[5], wp[6], wp[7]);
    };

    LOADT(0);
    WRITET(0);
    __syncthreads();
    int cur = 0;
    for (int it = 0; it < 16; ++it) {
        const bool more = (it < 15);
        if (more) LOADT((it + 1) * 64);         // issue next tile early (T14)
        const char* Ab = (const char*)Al[cur];
        const char* Wb = (const char*)Wl[cur];
#pragma unroll
        for (int ks = 0; ks < 2; ++ks) {
            const int kc = ks * 4 + lq;
            bf16x8 af[4], wf[2];
#pragma unroll
            for (int mf = 0; mf < 4; ++mf) {
                const int row = wm * 64 + mf * 16 + l15;
                af[mf] = *(const bf16x8*)(Ab + (row * 128 + ((kc * 16) ^ ((row & 7) << 4))));
            }
#pragma unroll
            for (int nf = 0; nf < 2; ++nf) {
                const int row = wn * 32 + nf * 16 + l15;
                wf[nf] = *(const bf16x8*)(Wb + (row * 128 + ((kc * 16) ^ ((row & 7) << 4))));
            }
#pragma unroll
            for (int mf = 0; mf < 4; ++mf)
#pragma unroll
                for (int nf = 0; nf < 2; ++nf)
                    acc[mf][nf] = __builtin_amdgcn_mfma_f32_16x16x32_bf16(af[mf], wf[nf], acc[mf][nf], 0, 0, 0);
        }
        if (more) WRITET(cur ^ 1);              // other buffer: no WAR with this iter's reads
        __syncthreads();
        cur ^= 1;
    }
    // Epilogue. C/D mapping: col = lane&15, row = (lane>>4)*4 + reg (m89-verified).
#pragma unroll
    for (int nf = 0; nf < 2; ++nf) {
        const int n = n0 + wn * 32 + nf * 16 + l15;
        const float bv = outb[n];
#pragma unroll
        for (int mf = 0; mf < 4; ++mf) {
            const int mbase = m0 + wm * 64 + mf * 16 + lq * 4;
#pragma unroll
            for (int r = 0; r < 4; ++r) {
                const int m = mbase + r;
                if (m < MROWS) {
                    const int bb = m & 63, tt = m >> 6;
                    out[((size_t)(bb * T + tt)) * V + n] = acc[mf][nf][r] + bv;
                }
            }
        }
    }
}

// Fallback (tight workspace): per-step logits, register-direct bf16 MFMA,
// f32 W stream + on-the-fly convert. Harness-verified in R2.
__global__ __launch_bounds__(256, 2)
void logits_mfma(const unsigned short* __restrict__ Abf, const float* __restrict__ Wf32,
                 const float* __restrict__ outb, float* __restrict__ C) {
    const int tid = threadIdx.x;
    const int l = tid & 63, w = tid >> 6;
    const int l15 = l & 15, lq = l >> 4;
    const int n = blockIdx.x * 64 + w * 16 + l15;
    const unsigned short* Ab = Abf + (size_t)l15 * H + lq * 8;
    const float* Wf = Wf32 + (size_t)n * H + lq * 8;
    const float bv = outb[n];
    f32x4 acc[4] = {};
#pragma unroll 4
    for (int k0 = 0; k0 < H; k0 += 32) {
        float4 w0 = *(const float4*)(Wf + k0);
        float4 w1 = *(const float4*)(Wf + k0 + 4);
        union { bf16x8 v; unsigned short u[8]; } cv;
        cv.u[0] = f2bf(w0.x); cv.u[1] = f2bf(w0.y); cv.u[2] = f2bf(w0.z); cv.u[3] = f2bf(w0.w);
        cv.u[4] = f2bf(w1.x); cv.u[5] = f2bf(w1.y); cv.u[6] = f2bf(w1.z); cv.u[7] = f2bf(w1.w);
        bf16x8 wf = cv.v;
        bf16x8 a0 = *(const bf16x8*)(Ab + k0);
        bf16x8 a1 = *(const bf16x8*)(Ab + 16 * H + k0);
        bf16x8 a2 = *(const bf16x8*)(Ab + 32 * H + k0);
        bf16x8 a3 = *(const bf16x8*)(Ab + 48 * H + k0);
        acc[0] = __builtin_amdgcn_mfma_f32_16x16x32_bf16(a0, wf, acc[0], 0, 0, 0);
        acc[1] = __builtin_amdgcn_mfma_f32_16x16x32_bf16(a1, wf, acc[1], 0, 0, 0);
        acc[2] = __builtin_amdgcn_mfma_f32_16x16x32_bf16(a2, wf, acc[2], 0, 0, 0);
        acc[3] = __builtin_amdgcn_mfma_f32_16x16x32_bf16(a3, wf, acc[3], 0, 0, 0);
    }
#pragma unroll
    for (int mf = 0; mf < 4; ++mf) {
        const int m = mf * 16 + lq * 4;
#pragma unroll
        for (int r = 0; r < 4; ++r)
            C[(size_t)(m + r) * ((size_t)T * V) + n] = acc[mf][r] + bv;
    }
}

// In-place log-softmax over V for one row of the logp slab (grid = 832 rows).
__global__ void logsoftmax_all(float* __restrict__ out) {
    const int tid = threadIdx.x;
    float* row = out + (size_t)blockIdx.x * V;
    float m = -3.4e38f;
    for (int v = tid; v < V; v += 256) m = fmaxf(m, row[v]);
#pragma unroll
    for (int o = 32; o; o >>= 1) m = fmaxf(m, __shfl_xor(m, o));
    __shared__ float red[4];
    if ((tid & 63) == 0) red[tid >> 6] = m;
    __syncthreads();
    m = fmaxf(fmaxf(red[0], red[1]), fmaxf(red[2], red[3]));
    float ssum = 0.f;
    for (int v = tid; v < V; v += 256) ssum += __expf(row[v] - m);
#pragma unroll
    for (int o = 32; o; o >>= 1) ssum += __shfl_xor(ssum, o);
    __shared__ float red2[4];
    if ((tid & 63) == 0) red2[tid >> 6] = ssum;
    __syncthreads();
    ssum = red2[0] + red2[1] + red2[2] + red2[3];
    float L = m + logf(ssum);
    for (int v = tid; v < V; v += 256) row[v] -= L;
}

// Copy two 64x1024 f32 buffers (used for h/c init and final h/c output).
__global__ void copy2(const float* __restrict__ a, const float* __restrict__ bsrc,
                      float* __restrict__ x, float* __restrict__ y) {
    size_t i = (size_t)blockIdx.x * 256 + threadIdx.x;
    ((float4*)x)[i] = ((const float4*)a)[i];
    ((float4*)y)[i] = ((const float4*)bsrc)[i];
}

extern "C" void kernel_launch(void* const* d_in, const int* in_sizes, int n_in,
                              void* d_out, int out_size, void* d_ws, size_t ws_size,
                              hipStream_t stream) {
    const float* enc_out = (const float*)d_in[0];
    const float* enc_h   = (const float*)d_in[1];
    const float* enc_c   = (const float*)d_in[2];
    const int*   target  = (const int*)d_in[3];
    const float* emb     = (const float*)d_in[4];
    const float* Wa      = (const float*)d_in[5];
    const float* ba      = (const float*)d_in[6];
    const float* Ua      = (const float*)d_in[7];
    const float* bu      = (const float*)d_in[8];
    const float* Va      = (const float*)d_in[9];
    // d_in[10] = bv: adds a constant to all scores -> cancels in softmax; omitted.
    const float* W_ih    = (const float*)d_in[11];
    const float* W_hh    = (const float*)d_in[12];
    const float* b_ih    = (const float*)d_in[13];
    const float* b_hh    = (const float*)d_in[14];
    const float* ln_g    = (const float*)d_in[15];
    const float* ln_b    = (const float*)d_in[16];
    const float* outW    = (const float*)d_in[17];
    const float* outb    = (const float*)d_in[18];
    float* out = (float*)d_out;

    float* ws    = (float*)d_ws;
    float* keys  = ws;                          // B*S*H f32
    float* h     = keys + (size_t)B * S * H;    // B*H
    float* c     = h + (size_t)B * H;           // B*H
    float* q     = c + (size_t)B * H;           // B*H
    float* xi    = q + (size_t)B * H;           // B*2H  (x | ctx)
    float* gates = xi + (size_t)B * 2 * H;      // B*4H
    // nh region: batched path wants T*B*H bf16 (3.4 MB); fallback needs B*H bf16.
    unsigned short* nhall = (unsigned short*)(gates + (size_t)B * 4 * H);

    const size_t base_bytes = ((size_t)B * S * H + 9 * (size_t)B * H) * sizeof(float);
    const size_t need_batched = base_bytes + (size_t)T * B * H * sizeof(unsigned short);
    const int batched = (ws_size >= need_batched);

    const size_t HOFF = (size_t)B * T * V;
    const size_t COFF = HOFF + (size_t)B * H;
    const size_t AOFF = COFF + (size_t)B * H;

    // keys_proj = enc_out @ Ua^T + bu   [B*S, H]
    hipLaunchKernelGGL(gemm_tn, dim3(H / 64, (B * S) / 64, 1), dim3(256), 0, stream,
                       enc_out, Ua, bu, keys, H, H, H);
    hipLaunchKernelGGL(copy2, dim3(64), dim3(256), 0, stream, enc_h, enc_c, h, c);

    for (int t = 0; t < T; ++t) {
        hipLaunchKernelGGL(embed_init, dim3(B), dim3(256), 0, stream,
                           target, emb, ba, b_ih, b_hh, xi, q, gates, t);
        // q = h @ Wa^T + ba   (split-K=4 atomic; bias pre-init in embed_init)
        hipLaunchKernelGGL(gemm_tn, dim3(H / 64, 1, 4), dim3(256), 0, stream,
                           h, Wa, nullptr, q, H, H, H);
        hipLaunchKernelGGL(attn_ctx, dim3(B), dim3(256), 0, stream,
                           q, keys, enc_out, Va, xi, out + AOFF, t);
        // gates = xi @ W_ih^T + h @ W_hh^T + b_ih + b_hh  (split-K atomic)
        hipLaunchKernelGGL(gemm_tn, dim3(4 * H / 64, 1, 4), dim3(256), 0, stream,
                           xi, W_ih, nullptr, gates, 4 * H, 2 * H, 4 * H);
        hipLaunchKernelGGL(gemm_tn, dim3(4 * H / 64, 1, 4), dim3(256), 0, stream,
                           h, W_hh, nullptr, gates, 4 * H, H, 4 * H);
        unsigned short* nh_t = batched ? (nhall + (size_t)t * B * H) : nhall;
        hipLaunchKernelGGL(cell_ln, dim3(B), dim3(256), 0, stream,
                           gates, h, c, nh_t, ln_g, ln_b);
        if (!batched)   // tight workspace: per-step logits (R2-verified path)
            hipLaunchKernelGGL(logits_mfma, dim3(V / 64), dim3(256), 0, stream,
                               nh_t, outW, outb, out + (size_t)t * V);
    }

    if (batched)
        // All 13 steps' logits in ONE GEMM (W read 7x from L3 instead of 13x per-step).
        hipLaunchKernelGGL(logits_batched, dim3(V / 64, (MROWS + 127) / 128), dim3(256), 0, stream,
                           nhall, outW, outb, out);
    // One log-softmax over all 832 rows (works for either logits path).
    hipLaunchKernelGGL(logsoftmax_all, dim3(MROWS), dim3(256), 0, stream, out);

    hipLaunchKernelGGL(copy2, dim3(64), dim3(256), 0, stream, h, c, out + HOFF, out + COFF);
}